// Round 4
// baseline (361.403 us; speedup 1.0000x reference)
//
#include <hip/hip_runtime.h>
#include <stdint.h>

#define NB 8
#define F_IN 6300
#define NT 500
#define HID 32
#define NOUT 20
#define NW 99   // mask words per (b,t) row: ceil(6300/64)

// float32 constants, rounded exactly as np.float32 would round the doubles
#define D_SR   0.7788007830714049f     // exp(-1/4)
#define S_SR   0.6795704571147613f     // e/4
#define D_REF  0.36787944117144233f    // exp(-1)
#define C_REF  -5.43656365691809f      // -2*e

// ---------------- K0: transpose w1 [32][6300] -> w1t [6300][32] ----------------
__global__ __launch_bounds__(256) void k0_transpose(const float* __restrict__ w1,
                                                    float* __restrict__ w1t) {
  int id = blockIdx.x * 256 + threadIdx.x;   // id = f*32 + o  (coalesced write)
  if (id >= F_IN * HID) return;
  int f = id >> 5, o = id & 31;
  w1t[id] = w1[o * F_IN + f];
}

// ---------------- K1: layer 1 (psp -> spike), exact f32, LDS-staged ----------------
// One wave per (b, 64-f word); block = 1 wave => NO barriers. 5 chunks of 100 t,
// global->LDS DMA double-buffered with fine-grained vmcnt waits (prefetch stays in
// flight across chunk boundaries). Masks laid out [b][wi][t] so stores coalesce.
#define CH_T 100
#define CH_I 25   // 16B-per-lane DMA instructions per chunk (4 t each)

__global__ __launch_bounds__(64) void k1_layer1(const float* __restrict__ x,
                                                uint64_t* __restrict__ masks) {
  __shared__ __align__(16) float lds[2][CH_I][256];  // 2 x 25.6 KB
  const int wi = blockIdx.x;          // 0..98
  const int b  = blockIdx.y;
  const int lane = threadIdx.x;
  int f = wi * 64 + lane;
  const float vm = (f < F_IN) ? 1.0f : 0.0f;
  if (f >= F_IN) f = F_IN - 1;        // clamp: loads stay in-bounds, input zeroed by vm
  const float* xrow = x + ((size_t)b * F_IN + f) * NT;
  uint64_t* mrow = masks + ((size_t)b * NW + wi) * NT;   // contiguous in t

  float z1 = 0.f, y1 = 0.f, zr = 0.f, yr = 0.f;

#define ISSUE(chunk, buf)                                                        \
  {                                                                              \
    const float* g = xrow + (chunk) * CH_T;                                      \
    _Pragma("unroll")                                                            \
    for (int j = 0; j < CH_I; j++) {                                             \
      __builtin_amdgcn_global_load_lds(                                          \
          (const __attribute__((address_space(1))) void*)(g + 4 * j),            \
          (__attribute__((address_space(3))) void*)&lds[buf][j][0], 16, 0, 0);   \
    }                                                                            \
  }

  ISSUE(0, 0)
  ISSUE(1, 1)
#pragma unroll
  for (int c = 0; c < 5; c++) {
    // chunk c guaranteed complete; chunk c+1's 25 DMA ops may remain in flight
    if (c == 4) { asm volatile("s_waitcnt vmcnt(0)" ::: "memory"); }
    else        { asm volatile("s_waitcnt vmcnt(25)" ::: "memory"); }
    const int buf = c & 1;
    uint64_t keep0 = 0, keep1 = 0;
#pragma unroll
    for (int j = 0; j < CH_I; j++) {
      float4 v = *(const float4*)&lds[buf][j][lane * 4];
      float xs[4] = {v.x * vm, v.y * vm, v.z * vm, v.w * vm};
#pragma unroll
      for (int e = 0; e < 4; e++) {
        const int tc = j * 4 + e;     // compile-time 0..99
        y1 = __fmul_rn(D_SR, __fadd_rn(y1, z1));        // y = d*(y+z)
        z1 = __fadd_rn(__fmul_rn(D_SR, z1), xs[e]);     // z = d*z + x
        float p = __fmul_rn(S_SR, y1);
        yr = __fmul_rn(D_REF, __fadd_rn(yr, zr));
        float u = __fadd_rn(p, __fmul_rn(C_REF, yr));
        bool s = (u >= 1.0f);
        zr = __fadd_rn(__fmul_rn(D_REF, zr), s ? 1.0f : 0.0f);
        uint64_t m = __ballot(s);
        if (tc < 64) { if (lane == tc)      keep0 = m; }
        else         { if (lane == tc - 64) keep1 = m; }
      }
    }
    // coalesced mask writeback: lane l -> t = c*100 + l (and +64)
    uint64_t* mp = mrow + c * CH_T;
    mp[lane] = keep0;
    if (lane < CH_T - 64) mp[64 + lane] = keep1;
    if (c + 2 < 5) ISSUE(c + 2, buf)
  }
#undef ISSUE
}

// ---------------- K2: sparse fc1: R[b,o,t] = sum_{f active} w1t[f][o] (f64) ----------------
__global__ __launch_bounds__(256) void k2_fc1(const float* __restrict__ w1t,
                                              const uint64_t* __restrict__ masks,
                                              double* __restrict__ R) {
  const int lane = threadIdx.x & 63;
  const int wave = threadIdx.x >> 6;
  const int half = lane >> 5;
  const int o = lane & 31;
  const int b = blockIdx.x;
  const int t = blockIdx.y * 4 + wave;        // blockIdx.y 0..124
  double acc = 0.0;
  for (int wi = half; wi < NW; wi += 2) {
    uint64_t m = masks[((size_t)b * NW + wi) * NT + t];
    const int base = wi * 64;
    while (m) {
      int i0 = __builtin_ctzll(m);  uint64_t m1 = m & (m - 1);
      int i1 = m1 ? __builtin_ctzll(m1) : i0;  uint64_t m2 = m1 ? (m1 & (m1 - 1)) : 0;
      int i2 = m2 ? __builtin_ctzll(m2) : i0;  uint64_t m3 = m2 ? (m2 & (m2 - 1)) : 0;
      int i3 = m3 ? __builtin_ctzll(m3) : i0;  m = m3 ? (m3 & (m3 - 1)) : 0;
      float a0 = w1t[(base + i0) * HID + o];
      float a1 = w1t[(base + i1) * HID + o];
      float a2 = w1t[(base + i2) * HID + o];
      float a3 = w1t[(base + i3) * HID + o];
      acc += (double)a0;
      if (m1) acc += (double)a1;
      if (m2) acc += (double)a2;
      if (m3) acc += (double)a3;
    }
  }
  int hi = __shfl_xor(__double2hiint(acc), 32);
  int lo = __shfl_xor(__double2loint(acc), 32);
  acc += __hiloint2double(hi, lo);
  if (half == 0) R[((size_t)b * HID + o) * NT + t] = acc;
}

// ---------------- shared f64 psp+spike step (layers 2/3) ----------------
__device__ __forceinline__ bool snn_step(double ri, double& z2, double& y2,
                                         double& zr, double& yr) {
  const double dsr = (double)D_SR, ssr = (double)S_SR;
  const double dre = (double)D_REF, cr = (double)C_REF;
  y2 = dsr * (y2 + z2);
  z2 = dsr * z2 + ri;
  double p = ssr * y2;
  yr = dre * (yr + zr);
  double u = p + cr * yr;
  bool s = (u >= 1.0);
  zr = dre * zr + (s ? 1.0 : 0.0);
  return s;
}

// ---------------- K3: layer-2 psp filter + spike -> s2 bytes [b][t][h] ----------------
// 4-group (16 t) static-register prefetch pipeline.
__global__ __launch_bounds__(256) void k3_spike2(const double* __restrict__ R,
                                                 uint8_t* __restrict__ s2) {
  int id = threadIdx.x;              // NB*HID = 256
  int b = id >> 5, h = id & 31;
  const double2* r2 = (const double2*)(R + (size_t)id * NT);
  uint8_t* sp = s2 + (size_t)b * NT * HID + h;
  double z2 = 0, y2 = 0, zr = 0, yr = 0;
  double2 g0a = r2[0], g0b = r2[1];
  double2 g1a = r2[2], g1b = r2[3];
  double2 g2a = r2[4], g2b = r2[5];
  double2 g3a = r2[6], g3b = r2[7];
  for (int g = 0; g < 125; g++) {
    sp[0]       = snn_step(g0a.x, z2, y2, zr, yr) ? 1 : 0;
    sp[HID]     = snn_step(g0a.y, z2, y2, zr, yr) ? 1 : 0;
    sp[2 * HID] = snn_step(g0b.x, z2, y2, zr, yr) ? 1 : 0;
    sp[3 * HID] = snn_step(g0b.y, z2, y2, zr, yr) ? 1 : 0;
    sp += 4 * HID;
    g0a = g1a; g0b = g1b; g1a = g2a; g1b = g2b; g2a = g3a; g2b = g3b;
    if (g + 4 < 125) { g3a = r2[(g + 4) * 2]; g3b = r2[(g + 4) * 2 + 1]; }
  }
}

// ---------------- K4: R3[b,o,t] = sum_h w2[o,h] * s2[b,t,h] (f64) ----------------
__global__ __launch_bounds__(256) void k4_fc2(const float* __restrict__ w2,
                                              const uint8_t* __restrict__ s2,
                                              double* __restrict__ R3) {
  int id = blockIdx.x * 256 + threadIdx.x;
  if (id >= NB * NOUT * NT) return;
  int t = id % NT;
  int bo = id / NT;
  int o = bo % NOUT;
  int b = bo / NOUT;
  const uint8_t* row = s2 + (size_t)(b * NT + t) * HID;
  const float* wr = w2 + o * HID;
  double acc = 0.0;
#pragma unroll
  for (int h = 0; h < HID; h += 4) {
    uint32_t m = *(const uint32_t*)(row + h);
    float4 w = *(const float4*)(wr + h);
    if (m & 0x000000FFu) acc += (double)w.x;
    if (m & 0x0000FF00u) acc += (double)w.y;
    if (m & 0x00FF0000u) acc += (double)w.z;
    if (m & 0xFF000000u) acc += (double)w.w;
  }
  R3[(size_t)bo * NT + t] = acc;
}

// ---------------- K5: layer-3 psp filter + spike -> output f32 ----------------
__global__ __launch_bounds__(256) void k5_out(const double* __restrict__ R3,
                                              float* __restrict__ out) {
  int id = threadIdx.x;
  if (id >= NB * NOUT) return;
  const double2* r2 = (const double2*)(R3 + (size_t)id * NT);
  float* orow = out + (size_t)id * NT;
  double z2 = 0, y2 = 0, zr = 0, yr = 0;
  double2 g0a = r2[0], g0b = r2[1];
  double2 g1a = r2[2], g1b = r2[3];
  double2 g2a = r2[4], g2b = r2[5];
  double2 g3a = r2[6], g3b = r2[7];
  for (int g = 0; g < 125; g++) {
    orow[0] = snn_step(g0a.x, z2, y2, zr, yr) ? 1.0f : 0.0f;
    orow[1] = snn_step(g0a.y, z2, y2, zr, yr) ? 1.0f : 0.0f;
    orow[2] = snn_step(g0b.x, z2, y2, zr, yr) ? 1.0f : 0.0f;
    orow[3] = snn_step(g0b.y, z2, y2, zr, yr) ? 1.0f : 0.0f;
    orow += 4;
    g0a = g1a; g0b = g1b; g1a = g2a; g1b = g2b; g2a = g3a; g2b = g3b;
    if (g + 4 < 125) { g3a = r2[(g + 4) * 2]; g3b = r2[(g + 4) * 2 + 1]; }
  }
}

extern "C" void kernel_launch(void* const* d_in, const int* in_sizes, int n_in,
                              void* d_out, int out_size, void* d_ws, size_t ws_size,
                              hipStream_t stream) {
  const float* x  = (const float*)d_in[0];   // [8,6300,500]
  const float* w1 = (const float*)d_in[1];   // [32,6300]
  const float* w2 = (const float*)d_in[2];   // [20,32]
  float* out = (float*)d_out;                // [8,20,500]

  uint8_t* ws = (uint8_t*)d_ws;
  const size_t W1T_BYTES  = (size_t)F_IN * HID * 4;        //   806,400
  const size_t MASK_BYTES = (size_t)NB * NW * NT * 8;      // 3,168,000
  const size_t R_BYTES    = (size_t)NB * HID * NT * 8;     // 1,024,000
  const size_t S2_BYTES   = (size_t)NB * NT * HID;         //   128,000
  float*    w1t   = (float*)ws;
  uint64_t* masks = (uint64_t*)(ws + W1T_BYTES);
  double*   R     = (double*)(ws + W1T_BYTES + MASK_BYTES);
  uint8_t*  s2    = ws + W1T_BYTES + MASK_BYTES + R_BYTES;
  double*   R3    = (double*)(ws + W1T_BYTES + MASK_BYTES + R_BYTES + S2_BYTES);

  k0_transpose<<<(F_IN * HID + 255) / 256, 256, 0, stream>>>(w1, w1t);
  k1_layer1<<<dim3(NW, NB), 64, 0, stream>>>(x, masks);
  k2_fc1<<<dim3(NB, NT / 4), 256, 0, stream>>>(w1t, masks, R);
  k3_spike2<<<1, 256, 0, stream>>>(R, s2);
  k4_fc2<<<(NB * NOUT * NT + 255) / 256, 256, 0, stream>>>(w2, s2, R3);
  k5_out<<<1, 256, 0, stream>>>(R3, out);
}

// Round 5
// 319.126 us; speedup vs baseline: 1.1325x; 1.1325x over previous
//
#include <hip/hip_runtime.h>
#include <stdint.h>

#define NB 8
#define F_IN 6300
#define NT 500
#define HID 32
#define NOUT 20
#define NW 99   // mask words per (b,t) row: ceil(6300/64)

// float32 constants, rounded exactly as np.float32 would round the doubles
#define D_SR   0.7788007830714049f     // exp(-1/4)
#define S_SR   0.6795704571147613f     // e/4
#define D_REF  0.36787944117144233f    // exp(-1)
#define C_REF  -5.43656365691809f      // -2*e

// ---------------- K0: transpose w1 [32][6300] -> w1t [6300][32] ----------------
__global__ __launch_bounds__(256) void k0_transpose(const float* __restrict__ w1,
                                                    float* __restrict__ w1t) {
  int id = blockIdx.x * 256 + threadIdx.x;   // id = f*32 + o  (coalesced write)
  if (id >= F_IN * HID) return;
  int f = id >> 5, o = id & 31;
  w1t[id] = w1[o * F_IN + f];
}

// ---------------- K1: layer 1 (psp -> spike), exact f32 ----------------
// One wave per (b, 64-f word); 1-wave blocks => no barriers. 5 chunks of 100 t.
// Loads are float4 ALONG t (coalesced, ~17 lines/instr, each line fully consumed
// in-instruction), transposed into LDS tile[100][65]; compute reads tile[t][lane]
// (conflict-free). Chunk c+1's global loads fly while chunk c computes.
#define CH_T 100

__global__ __launch_bounds__(64) void k1_layer1(const float* __restrict__ x,
                                                uint64_t* __restrict__ masks) {
  __shared__ float tile[CH_T][65];          // 26 KB -> 6 blocks/CU
  const int wi = blockIdx.x;                // 0..98
  const int b  = blockIdx.y;
  const int lane = threadIdx.x;
  const int f = wi * 64 + lane;
  const float vm = (f < F_IN) ? 1.0f : 0.0f;
  const float* xblk = x + (size_t)b * F_IN * NT;
  uint64_t* mrow = masks + ((size_t)b * NW + wi) * NT;   // contiguous in t

  // per-k load/deposit geometry: idx = k*64+lane in [0,1600) -> fid = idx/25, j = idx%25
  int goff[25];   // dword offset of float4 within this b's block: rf*NT + 4j
  int fidv[25], jv[25];
#pragma unroll
  for (int k = 0; k < 25; k++) {
    int idx = k * 64 + lane;
    int fid = idx / 25;
    int j = idx - fid * 25;
    int rf = wi * 64 + fid;
    if (rf >= F_IN) rf = F_IN - 1;          // clamp: in-bounds reads, zeroed by vm
    goff[k] = rf * NT + 4 * j;
    fidv[k] = fid;
    jv[k] = j;
  }

  float z1 = 0.f, y1 = 0.f, zr = 0.f, yr = 0.f;
  float4 ld[25];

  // prologue: fetch chunk 0
#pragma unroll
  for (int k = 0; k < 25; k++) ld[k] = *(const float4*)(xblk + goff[k]);

  for (int c = 0; c < 5; c++) {
    // deposit chunk c into LDS (transpose): tile[4j+e][fid]
#pragma unroll
    for (int k = 0; k < 25; k++) {
      int r = 4 * jv[k], fd = fidv[k];
      tile[r + 0][fd] = ld[k].x;
      tile[r + 1][fd] = ld[k].y;
      tile[r + 2][fd] = ld[k].z;
      tile[r + 3][fd] = ld[k].w;
    }
    // issue chunk c+1 global loads (fly during compute)
    if (c + 1 < 5) {
      const float* gb = xblk + (c + 1) * CH_T;
#pragma unroll
      for (int k = 0; k < 25; k++) ld[k] = *(const float4*)(gb + goff[k]);
    }
    // compute 100 t from tile (exact-order f32 recurrence)
    uint64_t keep0 = 0, keep1 = 0;
#pragma unroll
    for (int tc = 0; tc < CH_T; tc++) {
      float xi = tile[tc][lane] * vm;
      y1 = __fmul_rn(D_SR, __fadd_rn(y1, z1));        // y = d*(y+z)
      z1 = __fadd_rn(__fmul_rn(D_SR, z1), xi);        // z = d*z + x
      float p = __fmul_rn(S_SR, y1);
      yr = __fmul_rn(D_REF, __fadd_rn(yr, zr));
      float u = __fadd_rn(p, __fmul_rn(C_REF, yr));
      bool s = (u >= 1.0f);
      zr = __fadd_rn(__fmul_rn(D_REF, zr), s ? 1.0f : 0.0f);
      uint64_t m = __ballot(s);
      if (tc < 64) { if (lane == tc)      keep0 = m; }
      else         { if (lane == tc - 64) keep1 = m; }
    }
    // coalesced mask writeback: lane l -> t = c*100 + l (and +64)
    uint64_t* mp = mrow + c * CH_T;
    mp[lane] = keep0;
    if (lane < CH_T - 64) mp[64 + lane] = keep1;
  }
}

// ---------------- K2: sparse fc1: R[b,o,t] = sum_{f active} w1t[f][o] (f64) ----------------
__global__ __launch_bounds__(256) void k2_fc1(const float* __restrict__ w1t,
                                              const uint64_t* __restrict__ masks,
                                              double* __restrict__ R) {
  const int lane = threadIdx.x & 63;
  const int wave = threadIdx.x >> 6;
  const int half = lane >> 5;
  const int o = lane & 31;
  const int b = blockIdx.x;
  const int t = blockIdx.y * 4 + wave;        // blockIdx.y 0..124
  double acc = 0.0;
  for (int wi = half; wi < NW; wi += 2) {
    uint64_t m = masks[((size_t)b * NW + wi) * NT + t];
    const int base = wi * 64;
    while (m) {
      int i0 = __builtin_ctzll(m);  uint64_t m1 = m & (m - 1);
      int i1 = m1 ? __builtin_ctzll(m1) : i0;  uint64_t m2 = m1 ? (m1 & (m1 - 1)) : 0;
      int i2 = m2 ? __builtin_ctzll(m2) : i0;  uint64_t m3 = m2 ? (m2 & (m2 - 1)) : 0;
      int i3 = m3 ? __builtin_ctzll(m3) : i0;  m = m3 ? (m3 & (m3 - 1)) : 0;
      float a0 = w1t[(base + i0) * HID + o];
      float a1 = w1t[(base + i1) * HID + o];
      float a2 = w1t[(base + i2) * HID + o];
      float a3 = w1t[(base + i3) * HID + o];
      acc += (double)a0;
      if (m1) acc += (double)a1;
      if (m2) acc += (double)a2;
      if (m3) acc += (double)a3;
    }
  }
  int hi = __shfl_xor(__double2hiint(acc), 32);
  int lo = __shfl_xor(__double2loint(acc), 32);
  acc += __hiloint2double(hi, lo);
  if (half == 0) R[((size_t)b * HID + o) * NT + t] = acc;
}

// ---------------- shared f64 psp+spike step (layers 2/3) ----------------
__device__ __forceinline__ bool snn_step(double ri, double& z2, double& y2,
                                         double& zr, double& yr) {
  const double dsr = (double)D_SR, ssr = (double)S_SR;
  const double dre = (double)D_REF, cr = (double)C_REF;
  y2 = dsr * (y2 + z2);
  z2 = dsr * z2 + ri;
  double p = ssr * y2;
  yr = dre * (yr + zr);
  double u = p + cr * yr;
  bool s = (u >= 1.0);
  zr = dre * zr + (s ? 1.0 : 0.0);
  return s;
}

// ---------------- K3: layer-2 psp filter + spike -> s2 bytes [b][t][h] ----------------
// 64-thread blocks spread across CUs; 4-group (16 t) static-register pipeline.
__global__ __launch_bounds__(64) void k3_spike2(const double* __restrict__ R,
                                                uint8_t* __restrict__ s2) {
  int id = blockIdx.x * 64 + threadIdx.x;    // 0..255
  int b = id >> 5, h = id & 31;
  const double2* r2 = (const double2*)(R + (size_t)id * NT);
  uint8_t* sp = s2 + (size_t)b * NT * HID + h;
  double z2 = 0, y2 = 0, zr = 0, yr = 0;
  double2 g0a = r2[0], g0b = r2[1];
  double2 g1a = r2[2], g1b = r2[3];
  double2 g2a = r2[4], g2b = r2[5];
  double2 g3a = r2[6], g3b = r2[7];
  for (int g = 0; g < 125; g++) {
    sp[0]       = snn_step(g0a.x, z2, y2, zr, yr) ? 1 : 0;
    sp[HID]     = snn_step(g0a.y, z2, y2, zr, yr) ? 1 : 0;
    sp[2 * HID] = snn_step(g0b.x, z2, y2, zr, yr) ? 1 : 0;
    sp[3 * HID] = snn_step(g0b.y, z2, y2, zr, yr) ? 1 : 0;
    sp += 4 * HID;
    g0a = g1a; g0b = g1b; g1a = g2a; g1b = g2b; g2a = g3a; g2b = g3b;
    if (g + 4 < 125) { g3a = r2[(g + 4) * 2]; g3b = r2[(g + 4) * 2 + 1]; }
  }
}

// ---------------- K4: R3[b,o,t] = sum_h w2[o,h] * s2[b,t,h] (f64) ----------------
__global__ __launch_bounds__(256) void k4_fc2(const float* __restrict__ w2,
                                              const uint8_t* __restrict__ s2,
                                              double* __restrict__ R3) {
  int id = blockIdx.x * 256 + threadIdx.x;
  if (id >= NB * NOUT * NT) return;
  int t = id % NT;
  int bo = id / NT;
  int o = bo % NOUT;
  int b = bo / NOUT;
  const uint8_t* row = s2 + (size_t)(b * NT + t) * HID;
  const float* wr = w2 + o * HID;
  double acc = 0.0;
#pragma unroll
  for (int h = 0; h < HID; h += 4) {
    uint32_t m = *(const uint32_t*)(row + h);
    float4 w = *(const float4*)(wr + h);
    if (m & 0x000000FFu) acc += (double)w.x;
    if (m & 0x0000FF00u) acc += (double)w.y;
    if (m & 0x00FF0000u) acc += (double)w.z;
    if (m & 0xFF000000u) acc += (double)w.w;
  }
  R3[(size_t)bo * NT + t] = acc;
}

// ---------------- K5: layer-3 psp filter + spike -> output f32 ----------------
__global__ __launch_bounds__(64) void k5_out(const double* __restrict__ R3,
                                             float* __restrict__ out) {
  int id = blockIdx.x * 64 + threadIdx.x;
  if (id >= NB * NOUT) return;
  const double2* r2 = (const double2*)(R3 + (size_t)id * NT);
  float* orow = out + (size_t)id * NT;
  double z2 = 0, y2 = 0, zr = 0, yr = 0;
  double2 g0a = r2[0], g0b = r2[1];
  double2 g1a = r2[2], g1b = r2[3];
  double2 g2a = r2[4], g2b = r2[5];
  double2 g3a = r2[6], g3b = r2[7];
  for (int g = 0; g < 125; g++) {
    orow[0] = snn_step(g0a.x, z2, y2, zr, yr) ? 1.0f : 0.0f;
    orow[1] = snn_step(g0a.y, z2, y2, zr, yr) ? 1.0f : 0.0f;
    orow[2] = snn_step(g0b.x, z2, y2, zr, yr) ? 1.0f : 0.0f;
    orow[3] = snn_step(g0b.y, z2, y2, zr, yr) ? 1.0f : 0.0f;
    orow += 4;
    g0a = g1a; g0b = g1b; g1a = g2a; g1b = g2b; g2a = g3a; g2b = g3b;
    if (g + 4 < 125) { g3a = r2[(g + 4) * 2]; g3b = r2[(g + 4) * 2 + 1]; }
  }
}

extern "C" void kernel_launch(void* const* d_in, const int* in_sizes, int n_in,
                              void* d_out, int out_size, void* d_ws, size_t ws_size,
                              hipStream_t stream) {
  const float* x  = (const float*)d_in[0];   // [8,6300,500]
  const float* w1 = (const float*)d_in[1];   // [32,6300]
  const float* w2 = (const float*)d_in[2];   // [20,32]
  float* out = (float*)d_out;                // [8,20,500]

  uint8_t* ws = (uint8_t*)d_ws;
  const size_t W1T_BYTES  = (size_t)F_IN * HID * 4;        //   806,400
  const size_t MASK_BYTES = (size_t)NB * NW * NT * 8;      // 3,168,000
  const size_t R_BYTES    = (size_t)NB * HID * NT * 8;     // 1,024,000
  const size_t S2_BYTES   = (size_t)NB * NT * HID;         //   128,000
  float*    w1t   = (float*)ws;
  uint64_t* masks = (uint64_t*)(ws + W1T_BYTES);
  double*   R     = (double*)(ws + W1T_BYTES + MASK_BYTES);
  uint8_t*  s2    = ws + W1T_BYTES + MASK_BYTES + R_BYTES;
  double*   R3    = (double*)(ws + W1T_BYTES + MASK_BYTES + R_BYTES + S2_BYTES);

  k0_transpose<<<(F_IN * HID + 255) / 256, 256, 0, stream>>>(w1, w1t);
  k1_layer1<<<dim3(NW, NB), 64, 0, stream>>>(x, masks);
  k2_fc1<<<dim3(NB, NT / 4), 256, 0, stream>>>(w1t, masks, R);
  k3_spike2<<<4, 64, 0, stream>>>(R, s2);
  k4_fc2<<<(NB * NOUT * NT + 255) / 256, 256, 0, stream>>>(w2, s2, R3);
  k5_out<<<3, 64, 0, stream>>>(R3, out);
}